// Round 7
// baseline (138.107 us; speedup 1.0000x reference)
//
#include <hip/hip_runtime.h>
#include <hip/hip_bf16.h>
#include <stdint.h>

typedef unsigned short u16;
typedef __attribute__((ext_vector_type(8))) __bf16 bf16x8;
typedef __attribute__((ext_vector_type(4))) float f32x4;
typedef __attribute__((ext_vector_type(16))) float f32x16;

#define AS1(p) ((const __attribute__((address_space(1))) void*)(p))
#define AS3(p) ((__attribute__((address_space(3))) void*)(p))

__device__ __forceinline__ u16 f2bf(float f) {
  union { float f; uint32_t u; } c; c.f = f;
  uint32_t u = c.u;
  u += 0x7fffu + ((u >> 16) & 1u);   // RTNE
  return (u16)(u >> 16);
}

__device__ __forceinline__ float exp2_fast(float x) {
  float r; asm("v_exp_f32 %0, %1" : "=v"(r) : "v"(x)); return r;
}

__device__ __forceinline__ unsigned pkbf(float lo, float hi) {
  unsigned r;
  asm("v_cvt_pk_bf16_f32 %0, %1, %2" : "=v"(r) : "v"(lo), "v"(hi));
  return r;
}

// ---------------- fused cast fp32 -> bf16: 4 streams, one launch ----------------
__global__ __launch_bounds__(256) void cast4_f32_bf16(
    const float4* __restrict__ s0, ushort4* __restrict__ d0, int n0,
    const float4* __restrict__ s1, ushort4* __restrict__ d1, int n1,
    const float4* __restrict__ s2, ushort4* __restrict__ d2, int n2,
    const float4* __restrict__ s3, ushort4* __restrict__ d3, int n3) {
  int bid = blockIdx.x;
  const float4* src; ushort4* dst; int n4, b0, nb;
  if (bid < 512)       { src = s0; dst = d0; n4 = n0; b0 = 0;    nb = 512; }
  else if (bid < 1024) { src = s1; dst = d1; n4 = n1; b0 = 512;  nb = 512; }
  else if (bid < 1152) { src = s2; dst = d2; n4 = n2; b0 = 1024; nb = 128; }
  else                 { src = s3; dst = d3; n4 = n3; b0 = 1152; nb = 256; }
  int stride = nb * 256;
  for (int i = (bid - b0) * 256 + threadIdx.x; i < n4; i += stride) {
    float4 v = src[i];
    ushort4 o;
    o.x = f2bf(v.x); o.y = f2bf(v.y); o.z = f2bf(v.z); o.w = f2bf(v.w);
    dst[i] = o;
  }
}

// ---------------- fused NT GEMM (q + kv), bf16 global_load_lds, counted vmcnt ----------------
// 768 blocks (3/CU), XCD-swizzled so panel-sharing blocks land on one XCD's L2.
__global__ __launch_bounds__(256) void gemm_fused(const u16* __restrict__ xb,
                                                  const u16* __restrict__ wqb,
                                                  u16* __restrict__ qo,
                                                  const u16* __restrict__ cb,
                                                  const u16* __restrict__ wkb,
                                                  u16* __restrict__ kvo,
                                                  float scale_q) {
  __shared__ u16 As[2][128 * 32];
  __shared__ u16 Bs[2][128 * 32];
  const int K = 1024;
  // XCD swizzle: 768 = 8 XCDs x 96 contiguous workloads
  int bid = (blockIdx.x & 7) * 96 + (blockIdx.x >> 3);
  const u16 *A, *B; u16* C; int N, bm, bn; float scale;
  if (bid < 256) { A = xb; B = wqb; C = qo;  N = 1024; bm = bid >> 3; bn = bid & 7;  scale = scale_q; }
  else { int b2 = bid - 256; A = cb; B = wkb; C = kvo; N = 2048; bm = b2 >> 4; bn = b2 & 15; scale = 1.0f; }

  int tid = threadIdx.x;
  int w = tid >> 6, l = tid & 63;
  int wr = w >> 1, wc = w & 1;
  int lr = l & 15, lg = l >> 4;

  const u16* Abase = A + (size_t)(bm * 128 + (l >> 2)) * K + (l & 3) * 8;
  const u16* Bbase = B + (size_t)(bn * 128 + (l >> 2)) * K + (l & 3) * 8;

  f32x4 acc[4][4];
#pragma unroll
  for (int i = 0; i < 4; ++i)
#pragma unroll
    for (int j = 0; j < 4; ++j) acc[i][j] = (f32x4){0.f, 0.f, 0.f, 0.f};

#define STAGE(buf, k0)                                                              \
  {                                                                                 \
    _Pragma("unroll")                                                               \
    for (int t2 = 0; t2 < 2; ++t2) {                                                \
      int seg = w * 2 + t2;                                                         \
      __builtin_amdgcn_global_load_lds(AS1(Abase + (size_t)seg * 16 * K + (k0)),    \
                                       AS3(&As[buf][seg * 512]), 16, 0, 0);         \
      __builtin_amdgcn_global_load_lds(AS1(Bbase + (size_t)seg * 16 * K + (k0)),    \
                                       AS3(&Bs[buf][seg * 512]), 16, 0, 0);         \
    }                                                                               \
  }

  STAGE(0, 0);
  for (int t = 0; t < 32; ++t) {
    int cur = t & 1;
    if (t < 31) {
      STAGE(cur ^ 1, (t + 1) * 32);
      asm volatile("s_waitcnt vmcnt(4)" ::: "memory");
    } else {
      asm volatile("s_waitcnt vmcnt(0)" ::: "memory");
    }
    __builtin_amdgcn_s_barrier();
    bf16x8 af[4], bb[4];
#pragma unroll
    for (int i = 0; i < 4; ++i)
      af[i] = *(const bf16x8*)(&As[cur][(wr * 64 + i * 16 + lr) * 32 + lg * 8]);
#pragma unroll
    for (int j = 0; j < 4; ++j)
      bb[j] = *(const bf16x8*)(&Bs[cur][(wc * 64 + j * 16 + lr) * 32 + lg * 8]);
    asm volatile("s_waitcnt lgkmcnt(0)" ::: "memory");
    __builtin_amdgcn_sched_barrier(0);
#pragma unroll
    for (int i = 0; i < 4; ++i)
#pragma unroll
      for (int j = 0; j < 4; ++j)
        acc[i][j] = __builtin_amdgcn_mfma_f32_16x16x32_bf16(af[i], bb[j], acc[i][j], 0, 0, 0);
    __builtin_amdgcn_s_barrier();
  }
#undef STAGE

#pragma unroll
  for (int i = 0; i < 4; ++i)
#pragma unroll
    for (int j = 0; j < 4; ++j)
#pragma unroll
      for (int r = 0; r < 4; ++r) {
        int row = bm * 128 + wr * 64 + i * 16 + lg * 4 + r;
        int col = bn * 128 + wc * 64 + j * 16 + lr;
        C[(size_t)row * N + col] = f2bf(acc[i][j][r] * scale);
      }
}

// ---------------- flash attention v3: 2 waves x 64 q-rows (2x32 groups) ----------------
// Halves LDS-bytes/FLOP (K/V frags feed 2 q-groups). grid = 512 blocks (4/CU), 128 thr.
// Q pre-scaled by HD^-0.5*log2(e); exp2-domain softmax, defer-max THR=8.
#define SQ 2048
#define NT 32

__global__ __launch_bounds__(128, 2) void attn_kernel(const u16* __restrict__ Q,
                                                      const u16* __restrict__ KV,
                                                      float* __restrict__ O) {
  __shared__ u16 Ks[2 * 64 * 64];  // [buf][j][d], 16B-block bk holds dblk = bk ^ (j&7)
  __shared__ u16 Vt[2 * 64 * 64];  // [buf][d][j], byte = d*128 + ((j*2) ^ (((d^(d>>3))&7)<<4))

  // XCD swizzle: 512 = 8 x 64; consecutive workloads (same b,h KV) share an XCD L2
  int wgid = (blockIdx.x & 7) * 64 + (blockIdx.x >> 3);
  int qt = wgid & 15;
  int bh = wgid >> 4;
  int b = bh >> 4, h = bh & 15;
  int tid = threadIdx.x;
  int w = tid >> 6, l = tid & 63;
  int li = l & 31, hi = l >> 5;
  int jr8 = l >> 3, bk = l & 7;

  const u16* kbase = KV + (size_t)b * SQ * 2048 + (size_t)h * 64;
  const u16* vbase = kbase + 1024;
  int i0w = qt * 128 + w * 64;
  const u16* qrow0 = Q + (size_t)(b * SQ + i0w + li) * 1024 + h * 64;
  const u16* qrow1 = qrow0 + (size_t)32 * 1024;

  bf16x8 qA0 = *(const bf16x8*)(qrow0 + 0  + hi * 8);
  bf16x8 qA1 = *(const bf16x8*)(qrow0 + 16 + hi * 8);
  bf16x8 qA2 = *(const bf16x8*)(qrow0 + 32 + hi * 8);
  bf16x8 qA3 = *(const bf16x8*)(qrow0 + 48 + hi * 8);
  bf16x8 qB0 = *(const bf16x8*)(qrow1 + 0  + hi * 8);
  bf16x8 qB1 = *(const bf16x8*)(qrow1 + 16 + hi * 8);
  bf16x8 qB2 = *(const bf16x8*)(qrow1 + 32 + hi * 8);
  bf16x8 qB3 = *(const bf16x8*)(qrow1 + 48 + hi * 8);

  // prologue: stage tile 0 (K via gload_lds, 4 calls/thread = 64 rows; V -> regs)
#pragma unroll
  for (int c = 0; c < 4; ++c) {
    const u16* gk = kbase + (size_t)(w * 32 + c * 8 + jr8) * 2048 + ((bk ^ jr8) * 8);
    __builtin_amdgcn_global_load_lds(AS1(gk), AS3(Ks + w * 2048 + c * 512), 16, 0, 0);
  }
  uint4 vr0 = *(const uint4*)(vbase + (size_t)(0  + (tid >> 3)) * 2048 + (tid & 7) * 8);
  uint4 vr1 = *(const uint4*)(vbase + (size_t)(16 + (tid >> 3)) * 2048 + (tid & 7) * 8);
  uint4 vr2 = *(const uint4*)(vbase + (size_t)(32 + (tid >> 3)) * 2048 + (tid & 7) * 8);
  uint4 vr3 = *(const uint4*)(vbase + (size_t)(48 + (tid >> 3)) * 2048 + (tid & 7) * 8);

  float m0 = -1e30f, l0 = 0.f, m1 = -1e30f, l1 = 0.f;
  f32x16 acc0, acc1, acc2, acc3;
#pragma unroll
  for (int r = 0; r < 16; ++r) { acc0[r] = 0.f; acc1[r] = 0.f; acc2[r] = 0.f; acc3[r] = 0.f; }

  // softmax (log2 domain, defer-max) + in-place exp + bf16 pack into pw[16]
  auto softmax_pack = [&](f32x16& sA, f32x16& sB, float& m, float& lsum,
                          f32x16& aA, f32x16& aB, unsigned* pw) {
    float pm = fmaxf(sA[0], sA[1]);
#pragma unroll
    for (int r = 2; r < 16; r += 2) pm = fmaxf(fmaxf(pm, sA[r]), sA[r + 1]);
#pragma unroll
    for (int r = 0; r < 16; r += 2) pm = fmaxf(fmaxf(pm, sB[r]), sB[r + 1]);
    pm = fmaxf(pm, __shfl_xor(pm, 32));
    if (!__all(pm <= m + 8.0f)) {
      float mnew = fmaxf(m, pm);
      float esc = exp2_fast(m - mnew);
      m = mnew; lsum *= esc;
#pragma unroll
      for (int r = 0; r < 16; ++r) { aA[r] *= esc; aB[r] *= esc; }
    }
    float sum = 0.f;
#pragma unroll
    for (int r = 0; r < 16; ++r) { sA[r] = exp2_fast(sA[r] - m); sum += sA[r]; }
#pragma unroll
    for (int r = 0; r < 16; ++r) { sB[r] = exp2_fast(sB[r] - m); sum += sB[r]; }
    sum += __shfl_xor(sum, 32);
    lsum += sum;
#pragma unroll
    for (int i2 = 0; i2 < 8; ++i2) {
      pw[i2]     = pkbf(sA[2 * i2], sA[2 * i2 + 1]);
      pw[8 + i2] = pkbf(sB[2 * i2], sB[2 * i2 + 1]);
    }
#pragma unroll
    for (int gB = 0; gB < 2; ++gB) {
      int o = gB * 8;
      asm volatile("v_permlane32_swap_b32 %0, %1" : "+v"(pw[o + 0]), "+v"(pw[o + 2]));
      asm volatile("v_permlane32_swap_b32 %0, %1" : "+v"(pw[o + 1]), "+v"(pw[o + 3]));
      asm volatile("v_permlane32_swap_b32 %0, %1" : "+v"(pw[o + 4]), "+v"(pw[o + 6]));
      asm volatile("v_permlane32_swap_b32 %0, %1" : "+v"(pw[o + 5]), "+v"(pw[o + 7]));
    }
  };

  for (int t = 0; t < NT; ++t) {
    int cur = t & 1;
    u16* Ksc = Ks + cur * 4096;
    u16* Vtc = Vt + cur * 4096;
    __syncthreads();   // bar1: K(t) landed + V(t) regs ready (tile-old loads); bufs free
    // ---- V transpose-store (both waves, 64 rows total)
    {
      int a = tid & 7, jb = tid >> 3;
      const u16* p0_ = (const u16*)&vr0;
      const u16* p1_ = (const u16*)&vr1;
      const u16* p2_ = (const u16*)&vr2;
      const u16* p3_ = (const u16*)&vr3;
#pragma unroll
      for (int e = 0; e < 8; ++e) {
        int dbyte = (a * 8 + e) * 128, sw = (e ^ a) << 4;
        *(u16*)((char*)Vtc + dbyte + (((jb +  0) * 2) ^ sw)) = p0_[e];
        *(u16*)((char*)Vtc + dbyte + (((jb + 16) * 2) ^ sw)) = p1_[e];
        *(u16*)((char*)Vtc + dbyte + (((jb + 32) * 2) ^ sw)) = p2_[e];
        *(u16*)((char*)Vtc + dbyte + (((jb + 48) * 2) ^ sw)) = p3_[e];
      }
    }
    // ---- prefetch tile t+1 (rides through both barriers)
    if (t + 1 < NT) {
      int j0n = (t + 1) * 64;
      u16* Ksn = Ks + (cur ^ 1) * 4096;
#pragma unroll
      for (int c = 0; c < 4; ++c) {
        const u16* gk = kbase + (size_t)(j0n + w * 32 + c * 8 + jr8) * 2048 + ((bk ^ jr8) * 8);
        __builtin_amdgcn_global_load_lds(AS1(gk), AS3(Ksn + w * 2048 + c * 512), 16, 0, 0);
      }
      vr0 = *(const uint4*)(vbase + (size_t)(j0n +  0 + (tid >> 3)) * 2048 + (tid & 7) * 8);
      vr1 = *(const uint4*)(vbase + (size_t)(j0n + 16 + (tid >> 3)) * 2048 + (tid & 7) * 8);
      vr2 = *(const uint4*)(vbase + (size_t)(j0n + 32 + (tid >> 3)) * 2048 + (tid & 7) * 8);
      vr3 = *(const uint4*)(vbase + (size_t)(j0n + 48 + (tid >> 3)) * 2048 + (tid & 7) * 8);
    }
    // ---- swapped QK^T, both groups share K fragments
    f32x16 s0, s1, s2, s3;
#pragma unroll
    for (int r = 0; r < 16; ++r) { s0[r] = 0.f; s1[r] = 0.f; s2[r] = 0.f; s3[r] = 0.f; }
    int swk = (li & 7) << 4;
    __builtin_amdgcn_s_setprio(1);
#pragma unroll
    for (int kb = 0; kb < 4; ++kb) {
      bf16x8 k0 = *(const bf16x8*)((const char*)Ksc + li * 128        + ((kb * 32 + hi * 16) ^ swk));
      bf16x8 k1 = *(const bf16x8*)((const char*)Ksc + (32 + li) * 128 + ((kb * 32 + hi * 16) ^ swk));
      bf16x8 qa = (kb == 0) ? qA0 : (kb == 1) ? qA1 : (kb == 2) ? qA2 : qA3;
      bf16x8 qb = (kb == 0) ? qB0 : (kb == 1) ? qB1 : (kb == 2) ? qB2 : qB3;
      s0 = __builtin_amdgcn_mfma_f32_32x32x16_bf16(k0, qa, s0, 0, 0, 0);
      s2 = __builtin_amdgcn_mfma_f32_32x32x16_bf16(k0, qb, s2, 0, 0, 0);
      s1 = __builtin_amdgcn_mfma_f32_32x32x16_bf16(k1, qa, s1, 0, 0, 0);
      s3 = __builtin_amdgcn_mfma_f32_32x32x16_bf16(k1, qb, s3, 0, 0, 0);
    }
    __builtin_amdgcn_s_setprio(0);
    asm volatile("s_waitcnt lgkmcnt(0)" ::: "memory");   // my ds_writes committed
    __builtin_amdgcn_s_barrier();                        // bar2: Vt[cur] visible (no vmcnt drain)
    // ---- softmax both groups (g1 VALU overlaps nothing in-wave, but other wave's PV on SIMD)
    unsigned pw0[16], pw1[16];
    softmax_pack(s0, s1, m0, l0, acc0, acc1, pw0);
    softmax_pack(s2, s3, m1, l1, acc2, acc3, pw1);
    // ---- PV, V fragments shared between groups
    __builtin_amdgcn_s_setprio(1);
#pragma unroll
    for (int kb2 = 0; kb2 < 4; ++kb2) {
      int jbyte = kb2 * 32 + hi * 16;
      int d0_ = li, d1_ = 32 + li;
      bf16x8 v0 = *(const bf16x8*)((const char*)Vtc + d0_ * 128 + (jbyte ^ (((d0_ ^ (d0_ >> 3)) & 7) << 4)));
      bf16x8 v1 = *(const bf16x8*)((const char*)Vtc + d1_ * 128 + (jbyte ^ (((d1_ ^ (d1_ >> 3)) & 7) << 4)));
      uint4 u0; u0.x = pw0[kb2 * 4 + 0]; u0.y = pw0[kb2 * 4 + 1]; u0.z = pw0[kb2 * 4 + 2]; u0.w = pw0[kb2 * 4 + 3];
      uint4 u1; u1.x = pw1[kb2 * 4 + 0]; u1.y = pw1[kb2 * 4 + 1]; u1.z = pw1[kb2 * 4 + 2]; u1.w = pw1[kb2 * 4 + 3];
      bf16x8 pa0 = *(bf16x8*)&u0;
      bf16x8 pa1 = *(bf16x8*)&u1;
      acc0 = __builtin_amdgcn_mfma_f32_32x32x16_bf16(v0, pa0, acc0, 0, 0, 0);
      acc2 = __builtin_amdgcn_mfma_f32_32x32x16_bf16(v0, pa1, acc2, 0, 0, 0);
      acc1 = __builtin_amdgcn_mfma_f32_32x32x16_bf16(v1, pa0, acc1, 0, 0, 0);
      acc3 = __builtin_amdgcn_mfma_f32_32x32x16_bf16(v1, pa1, acc3, 0, 0, 0);
    }
    __builtin_amdgcn_s_setprio(0);
  }
  // ---- epilogue: O^T layout, d = db*32 + 8g + 4hi + r, col(q-row) = li (+32 for g1)
  float inv0 = 1.f / l0, inv1 = 1.f / l1;
  float* orow0 = O + ((size_t)(b * SQ + i0w + li) * 1024 + h * 64);
  float* orow1 = orow0 + (size_t)32 * 1024;
#pragma unroll
  for (int g = 0; g < 4; ++g) {
    f32x4 oA0, oA1, oB0, oB1;
#pragma unroll
    for (int q_ = 0; q_ < 4; ++q_) {
      oA0[q_] = acc0[g * 4 + q_] * inv0;
      oA1[q_] = acc1[g * 4 + q_] * inv0;
      oB0[q_] = acc2[g * 4 + q_] * inv1;
      oB1[q_] = acc3[g * 4 + q_] * inv1;
    }
    *(f32x4*)(orow0 + 8 * g + 4 * hi) = oA0;
    *(f32x4*)(orow0 + 32 + 8 * g + 4 * hi) = oA1;
    *(f32x4*)(orow1 + 8 * g + 4 * hi) = oB0;
    *(f32x4*)(orow1 + 32 + 8 * g + 4 * hi) = oB1;
  }
}

extern "C" void kernel_launch(void* const* d_in, const int* in_sizes, int n_in,
                              void* d_out, int out_size, void* d_ws, size_t ws_size,
                              hipStream_t stream) {
  (void)in_sizes; (void)n_in; (void)out_size; (void)ws_size;
  const float* x   = (const float*)d_in[0];
  const float* ctx = (const float*)d_in[1];
  const float* Wq  = (const float*)d_in[2];
  const float* Wkv = (const float*)d_in[3];
  float* out = (float*)d_out;
  char* ws = (char*)d_ws;

  u16* xb  = (u16*)(ws);                       // x bf16   [4096][1024]  8 MB
  u16* cb  = (u16*)(ws + (8ull  << 20));       // ctx bf16 [4096][1024]  8 MB
  u16* wqb = (u16*)(ws + (16ull << 20));       // Wq bf16  [1024][1024]  2 MB
  u16* wkb = (u16*)(ws + (18ull << 20));       // Wkv bf16 [2048][1024]  4 MB
  u16* q   = (u16*)(ws + (22ull << 20));       // q bf16, pre-scaled by 0.125*log2(e)
  u16* kv  = (u16*)(ws + (30ull << 20));       // kv bf16  [4096][2048] 16 MB

  cast4_f32_bf16<<<1408, 256, 0, stream>>>(
      (const float4*)x,   (ushort4*)xb,  (4096 * 1024) / 4,
      (const float4*)ctx, (ushort4*)cb,  (4096 * 1024) / 4,
      (const float4*)Wq,  (ushort4*)wqb, (1024 * 1024) / 4,
      (const float4*)Wkv, (ushort4*)wkb, (2048 * 1024) / 4);

  gemm_fused<<<768, 256, 0, stream>>>(xb, wqb, q, cb, wkb, kv, 0.125f * 1.44269504f);

  attn_kernel<<<512, 128, 0, stream>>>(q, kv, out);
}

// Round 8
// 106.861 us; speedup vs baseline: 1.2924x; 1.2924x over previous
//
#include <hip/hip_runtime.h>
#include <hip/hip_bf16.h>
#include <stdint.h>

typedef unsigned short u16;
typedef __attribute__((ext_vector_type(8))) __bf16 bf16x8;
typedef __attribute__((ext_vector_type(4))) float f32x4;
typedef __attribute__((ext_vector_type(16))) float f32x16;

#define AS1(p) ((const __attribute__((address_space(1))) void*)(p))
#define AS3(p) ((__attribute__((address_space(3))) void*)(p))

__device__ __forceinline__ u16 f2bf(float f) {
  union { float f; uint32_t u; } c; c.f = f;
  uint32_t u = c.u;
  u += 0x7fffu + ((u >> 16) & 1u);   // RTNE
  return (u16)(u >> 16);
}

__device__ __forceinline__ float exp2_fast(float x) {
  float r; asm("v_exp_f32 %0, %1" : "=v"(r) : "v"(x)); return r;
}

// ---------------- fused cast fp32 -> bf16: 4 streams, one launch ----------------
__global__ __launch_bounds__(256) void cast4_f32_bf16(
    const float4* __restrict__ s0, ushort4* __restrict__ d0, int n0,
    const float4* __restrict__ s1, ushort4* __restrict__ d1, int n1,
    const float4* __restrict__ s2, ushort4* __restrict__ d2, int n2,
    const float4* __restrict__ s3, ushort4* __restrict__ d3, int n3) {
  int bid = blockIdx.x;
  const float4* src; ushort4* dst; int n4, b0, nb;
  if (bid < 512)       { src = s0; dst = d0; n4 = n0; b0 = 0;    nb = 512; }
  else if (bid < 1024) { src = s1; dst = d1; n4 = n1; b0 = 512;  nb = 512; }
  else if (bid < 1152) { src = s2; dst = d2; n4 = n2; b0 = 1024; nb = 128; }
  else                 { src = s3; dst = d3; n4 = n3; b0 = 1152; nb = 256; }
  int stride = nb * 256;
  for (int i = (bid - b0) * 256 + threadIdx.x; i < n4; i += stride) {
    float4 v = src[i];
    ushort4 o;
    o.x = f2bf(v.x); o.y = f2bf(v.y); o.z = f2bf(v.z); o.w = f2bf(v.w);
    dst[i] = o;
  }
}

// ---------------- fused NT GEMM (q + kv), bf16 global_load_lds, counted vmcnt ----------------
// 768 blocks (3/CU), XCD-swizzled so panel-sharing blocks land on one XCD's L2.
__global__ __launch_bounds__(256) void gemm_fused(const u16* __restrict__ xb,
                                                  const u16* __restrict__ wqb,
                                                  u16* __restrict__ qo,
                                                  const u16* __restrict__ cb,
                                                  const u16* __restrict__ wkb,
                                                  u16* __restrict__ kvo,
                                                  float scale_q) {
  __shared__ u16 As[2][128 * 32];
  __shared__ u16 Bs[2][128 * 32];
  const int K = 1024;
  // XCD swizzle: 768 = 8 XCDs x 96 contiguous workloads
  int bid = (blockIdx.x & 7) * 96 + (blockIdx.x >> 3);
  const u16 *A, *B; u16* C; int N, bm, bn; float scale;
  if (bid < 256) { A = xb; B = wqb; C = qo;  N = 1024; bm = bid >> 3; bn = bid & 7;  scale = scale_q; }
  else { int b2 = bid - 256; A = cb; B = wkb; C = kvo; N = 2048; bm = b2 >> 4; bn = b2 & 15; scale = 1.0f; }

  int tid = threadIdx.x;
  int w = tid >> 6, l = tid & 63;
  int wr = w >> 1, wc = w & 1;
  int lr = l & 15, lg = l >> 4;

  const u16* Abase = A + (size_t)(bm * 128 + (l >> 2)) * K + (l & 3) * 8;
  const u16* Bbase = B + (size_t)(bn * 128 + (l >> 2)) * K + (l & 3) * 8;

  f32x4 acc[4][4];
#pragma unroll
  for (int i = 0; i < 4; ++i)
#pragma unroll
    for (int j = 0; j < 4; ++j) acc[i][j] = (f32x4){0.f, 0.f, 0.f, 0.f};

#define STAGE(buf, k0)                                                              \
  {                                                                                 \
    _Pragma("unroll")                                                               \
    for (int t2 = 0; t2 < 2; ++t2) {                                                \
      int seg = w * 2 + t2;                                                         \
      __builtin_amdgcn_global_load_lds(AS1(Abase + (size_t)seg * 16 * K + (k0)),    \
                                       AS3(&As[buf][seg * 512]), 16, 0, 0);         \
      __builtin_amdgcn_global_load_lds(AS1(Bbase + (size_t)seg * 16 * K + (k0)),    \
                                       AS3(&Bs[buf][seg * 512]), 16, 0, 0);         \
    }                                                                               \
  }

  STAGE(0, 0);
  for (int t = 0; t < 32; ++t) {
    int cur = t & 1;
    if (t < 31) {
      STAGE(cur ^ 1, (t + 1) * 32);
      asm volatile("s_waitcnt vmcnt(4)" ::: "memory");
    } else {
      asm volatile("s_waitcnt vmcnt(0)" ::: "memory");
    }
    __builtin_amdgcn_s_barrier();
    bf16x8 af[4], bb[4];
#pragma unroll
    for (int i = 0; i < 4; ++i)
      af[i] = *(const bf16x8*)(&As[cur][(wr * 64 + i * 16 + lr) * 32 + lg * 8]);
#pragma unroll
    for (int j = 0; j < 4; ++j)
      bb[j] = *(const bf16x8*)(&Bs[cur][(wc * 64 + j * 16 + lr) * 32 + lg * 8]);
    asm volatile("s_waitcnt lgkmcnt(0)" ::: "memory");
    __builtin_amdgcn_sched_barrier(0);
#pragma unroll
    for (int i = 0; i < 4; ++i)
#pragma unroll
      for (int j = 0; j < 4; ++j)
        acc[i][j] = __builtin_amdgcn_mfma_f32_16x16x32_bf16(af[i], bb[j], acc[i][j], 0, 0, 0);
    __builtin_amdgcn_s_barrier();
  }
#undef STAGE

#pragma unroll
  for (int i = 0; i < 4; ++i)
#pragma unroll
    for (int j = 0; j < 4; ++j)
#pragma unroll
      for (int r = 0; r < 4; ++r) {
        int row = bm * 128 + wr * 64 + i * 16 + lg * 4 + r;
        int col = bn * 128 + wc * 64 + j * 16 + lr;
        C[(size_t)row * N + col] = f2bf(acc[i][j][r] * scale);
      }
}

// ---------------- flash attention: T15 double-pipeline, 32x32 swapped QK^T ----------------
// grid = 512 blocks (2/CU), 256 thr (4 waves x 32 q-rows). One barrier per tile.
// XCD-swizzled: consecutive wgids share one head's KV panel per XCD L2 (r7: FETCH 70->12MB).
#define SQ 2048
#define NT 32

__global__ __launch_bounds__(256, 2) void attn_kernel(const u16* __restrict__ Q,
                                                      const u16* __restrict__ KV,
                                                      float* __restrict__ O) {
  __shared__ u16 Ks[2 * 64 * 64];  // [buf][j][d], 16B-block bk holds dblk = bk ^ (j&7)
  __shared__ u16 Vt[2 * 64 * 64];  // [buf][d][j], byte = d*128 + ((j*2) ^ (((d^(d>>3))&7)<<4))

  int wgid = (blockIdx.x & 7) * 64 + (blockIdx.x >> 3);   // bijective 8x64 XCD swizzle
  int qt = wgid & 15;
  int bh = wgid >> 4;
  int b = bh >> 4, h = bh & 15;
  int tid = threadIdx.x;
  int w = tid >> 6, l = tid & 63;
  int li = l & 31, hi = l >> 5;
  int jr = l >> 3, bk = l & 7;

  const u16* kbase = KV + (size_t)b * SQ * 2048 + (size_t)h * 64;
  const u16* vbase = kbase + 1024;
  int i0g = qt * 128 + w * 32;
  const u16* qrow = Q + (size_t)(b * SQ + i0g + li) * 1024 + h * 64;

  bf16x8 qf0 = *(const bf16x8*)(qrow + 0  + hi * 8);
  bf16x8 qf1 = *(const bf16x8*)(qrow + 16 + hi * 8);
  bf16x8 qf2 = *(const bf16x8*)(qrow + 32 + hi * 8);
  bf16x8 qf3 = *(const bf16x8*)(qrow + 48 + hi * 8);

  // prologue: stage tile 0
  {
    const u16* gk0 = kbase + (size_t)(w * 8 + jr) * 2048 + ((bk ^ jr) * 8);
    __builtin_amdgcn_global_load_lds(AS1(gk0), AS3(Ks + w * 512), 16, 0, 0);
    const u16* gk1 = kbase + (size_t)(32 + w * 8 + jr) * 2048 + ((bk ^ jr) * 8);
    __builtin_amdgcn_global_load_lds(AS1(gk1), AS3(Ks + 2048 + w * 512), 16, 0, 0);
  }
  uint4 vregA = *(const uint4*)(vbase + (size_t)(tid >> 3) * 2048 + (tid & 7) * 8);
  uint4 vregB = *(const uint4*)(vbase + (size_t)(32 + (tid >> 3)) * 2048 + (tid & 7) * 8);

  float m_run = -1e30f, l_run = 0.f;
  f32x16 acc0, acc1;
#pragma unroll
  for (int r = 0; r < 16; ++r) { acc0[r] = 0.f; acc1[r] = 0.f; }

  auto stage_pf = [&](int t) {
    u16* Vtc = Vt + (t & 1) * 4096;
    int a = tid & 7, jj0 = tid >> 3;
    const u16* pa_ = (const u16*)&vregA;
#pragma unroll
    for (int e = 0; e < 8; ++e)
      *(u16*)((char*)Vtc + (a * 8 + e) * 128 + ((jj0 * 2) ^ ((e ^ a) << 4))) = pa_[e];
    const u16* pb_ = (const u16*)&vregB;
    int jj1 = 32 + jj0;
#pragma unroll
    for (int e = 0; e < 8; ++e)
      *(u16*)((char*)Vtc + (a * 8 + e) * 128 + ((jj1 * 2) ^ ((e ^ a) << 4))) = pb_[e];
    if (t + 1 < NT) {
      int j0n = (t + 1) * 64;
      u16* Ksn = Ks + ((t + 1) & 1) * 4096;
      const u16* gk0 = kbase + (size_t)(j0n + w * 8 + jr) * 2048 + ((bk ^ jr) * 8);
      __builtin_amdgcn_global_load_lds(AS1(gk0), AS3(Ksn + w * 512), 16, 0, 0);
      const u16* gk1 = kbase + (size_t)(j0n + 32 + w * 8 + jr) * 2048 + ((bk ^ jr) * 8);
      __builtin_amdgcn_global_load_lds(AS1(gk1), AS3(Ksn + 2048 + w * 512), 16, 0, 0);
      vregA = *(const uint4*)(vbase + (size_t)(j0n + (tid >> 3)) * 2048 + (tid & 7) * 8);
      vregB = *(const uint4*)(vbase + (size_t)(j0n + 32 + (tid >> 3)) * 2048 + (tid & 7) * 8);
    }
  };

  auto qkt = [&](int t, f32x16& n0, f32x16& n1) {
    const u16* Ksc = Ks + (t & 1) * 4096;
#pragma unroll
    for (int r = 0; r < 16; ++r) { n0[r] = 0.f; n1[r] = 0.f; }
    int swk = (li & 7) << 4;
    __builtin_amdgcn_s_setprio(1);
#pragma unroll
    for (int kb = 0; kb < 4; ++kb) {
      bf16x8 k0 = *(const bf16x8*)((const char*)Ksc + li * 128        + ((kb * 32 + hi * 16) ^ swk));
      bf16x8 k1 = *(const bf16x8*)((const char*)Ksc + (32 + li) * 128 + ((kb * 32 + hi * 16) ^ swk));
      bf16x8 qq = (kb == 0) ? qf0 : (kb == 1) ? qf1 : (kb == 2) ? qf2 : qf3;
      n0 = __builtin_amdgcn_mfma_f32_32x32x16_bf16(k0, qq, n0, 0, 0, 0);
      n1 = __builtin_amdgcn_mfma_f32_32x32x16_bf16(k1, qq, n1, 0, 0, 0);
    }
    __builtin_amdgcn_s_setprio(0);
  };

  auto finish_pv = [&](int tp, const f32x16& sp0, const f32x16& sp1) {
    const u16* Vtp = Vt + (tp & 1) * 4096;
    float p0[16], p1[16];
    float sum = 0.f;
#pragma unroll
    for (int r = 0; r < 16; ++r) { p0[r] = exp2_fast(sp0[r] - m_run); sum += p0[r]; }
#pragma unroll
    for (int r = 0; r < 16; ++r) { p1[r] = exp2_fast(sp1[r] - m_run); sum += p1[r]; }
    sum += __shfl_xor(sum, 32);
    l_run += sum;
    unsigned pw[16];
#pragma unroll
    for (int i2 = 0; i2 < 8; ++i2) {
      asm("v_cvt_pk_bf16_f32 %0, %1, %2" : "=v"(pw[i2])     : "v"(p0[2 * i2]), "v"(p0[2 * i2 + 1]));
      asm("v_cvt_pk_bf16_f32 %0, %1, %2" : "=v"(pw[8 + i2]) : "v"(p1[2 * i2]), "v"(p1[2 * i2 + 1]));
    }
#pragma unroll
    for (int gB = 0; gB < 2; ++gB) {
      int o = gB * 8;
      asm volatile("v_permlane32_swap_b32 %0, %1" : "+v"(pw[o + 0]), "+v"(pw[o + 2]));
      asm volatile("v_permlane32_swap_b32 %0, %1" : "+v"(pw[o + 1]), "+v"(pw[o + 3]));
      asm volatile("v_permlane32_swap_b32 %0, %1" : "+v"(pw[o + 4]), "+v"(pw[o + 6]));
      asm volatile("v_permlane32_swap_b32 %0, %1" : "+v"(pw[o + 5]), "+v"(pw[o + 7]));
    }
    __builtin_amdgcn_s_setprio(1);
#pragma unroll
    for (int kb2 = 0; kb2 < 4; ++kb2) {
      uint4 ufr;
      ufr.x = pw[kb2 * 4 + 0]; ufr.y = pw[kb2 * 4 + 1];
      ufr.z = pw[kb2 * 4 + 2]; ufr.w = pw[kb2 * 4 + 3];
      bf16x8 pa = *(bf16x8*)&ufr;
      int jbyte = kb2 * 32 + hi * 16;
      int d0_ = li, d1_ = 32 + li;
      bf16x8 v0 = *(const bf16x8*)((const char*)Vtp + d0_ * 128 + (jbyte ^ (((d0_ ^ (d0_ >> 3)) & 7) << 4)));
      bf16x8 v1 = *(const bf16x8*)((const char*)Vtp + d1_ * 128 + (jbyte ^ (((d1_ ^ (d1_ >> 3)) & 7) << 4)));
      acc0 = __builtin_amdgcn_mfma_f32_32x32x16_bf16(v0, pa, acc0, 0, 0, 0);
      acc1 = __builtin_amdgcn_mfma_f32_32x32x16_bf16(v1, pa, acc1, 0, 0, 0);
    }
    __builtin_amdgcn_s_setprio(0);
  };

  auto maxred = [&](const f32x16& n0, const f32x16& n1) {
    float pm = fmaxf(n0[0], n0[1]);
#pragma unroll
    for (int r = 2; r < 16; r += 2) pm = fmaxf(fmaxf(pm, n0[r]), n0[r + 1]);
#pragma unroll
    for (int r = 0; r < 16; r += 2) pm = fmaxf(fmaxf(pm, n1[r]), n1[r + 1]);
    pm = fmaxf(pm, __shfl_xor(pm, 32));
    if (!__all(pm <= m_run + 8.0f)) {
      float mnew = fmaxf(m_run, pm);
      float esc = exp2_fast(m_run - mnew);
      m_run = mnew;
      l_run *= esc;
#pragma unroll
      for (int r = 0; r < 16; ++r) { acc0[r] *= esc; acc1[r] *= esc; }
    }
  };

  f32x16 sa0, sa1, sb0, sb1;
  __syncthreads();                 // K(0) landed
  stage_pf(0);
  qkt(0, sa0, sa1);
  maxred(sa0, sa1);
  for (int t = 1; t < NT - 1; t += 2) {
    __syncthreads();
    stage_pf(t);
    qkt(t, sb0, sb1);
    finish_pv(t - 1, sa0, sa1);
    maxred(sb0, sb1);
    __syncthreads();
    stage_pf(t + 1);
    qkt(t + 1, sa0, sa1);
    finish_pv(t, sb0, sb1);
    maxred(sa0, sa1);
  }
  __syncthreads();
  stage_pf(NT - 1);
  qkt(NT - 1, sb0, sb1);
  finish_pv(NT - 2, sa0, sa1);
  maxred(sb0, sb1);
  __syncthreads();
  finish_pv(NT - 1, sb0, sb1);

  float inv = 1.f / l_run;
  float* orow = O + ((size_t)(b * SQ + i0g + li) * 1024 + h * 64);
#pragma unroll
  for (int g = 0; g < 4; ++g) {
    f32x4 o0, o1;
#pragma unroll
    for (int q_ = 0; q_ < 4; ++q_) {
      o0[q_] = acc0[g * 4 + q_] * inv;
      o1[q_] = acc1[g * 4 + q_] * inv;
    }
    *(f32x4*)(orow + 8 * g + 4 * hi) = o0;
    *(f32x4*)(orow + 32 + 8 * g + 4 * hi) = o1;
  }
}

extern "C" void kernel_launch(void* const* d_in, const int* in_sizes, int n_in,
                              void* d_out, int out_size, void* d_ws, size_t ws_size,
                              hipStream_t stream) {
  (void)in_sizes; (void)n_in; (void)out_size; (void)ws_size;
  const float* x   = (const float*)d_in[0];
  const float* ctx = (const float*)d_in[1];
  const float* Wq  = (const float*)d_in[2];
  const float* Wkv = (const float*)d_in[3];
  float* out = (float*)d_out;
  char* ws = (char*)d_ws;

  u16* xb  = (u16*)(ws);                       // x bf16   [4096][1024]  8 MB
  u16* cb  = (u16*)(ws + (8ull  << 20));       // ctx bf16 [4096][1024]  8 MB
  u16* wqb = (u16*)(ws + (16ull << 20));       // Wq bf16  [1024][1024]  2 MB
  u16* wkb = (u16*)(ws + (18ull << 20));       // Wkv bf16 [2048][1024]  4 MB
  u16* q   = (u16*)(ws + (22ull << 20));       // q bf16, pre-scaled by 0.125*log2(e)
  u16* kv  = (u16*)(ws + (30ull << 20));       // kv bf16  [4096][2048] 16 MB

  cast4_f32_bf16<<<1408, 256, 0, stream>>>(
      (const float4*)x,   (ushort4*)xb,  (4096 * 1024) / 4,
      (const float4*)ctx, (ushort4*)cb,  (4096 * 1024) / 4,
      (const float4*)Wq,  (ushort4*)wqb, (1024 * 1024) / 4,
      (const float4*)Wkv, (ushort4*)wkb, (2048 * 1024) / 4);

  gemm_fused<<<768, 256, 0, stream>>>(xb, wqb, q, cb, wkb, kv, 0.125f * 1.44269504f);

  attn_kernel<<<512, 256, 0, stream>>>(q, kv, out);
}

// Round 10
// 103.880 us; speedup vs baseline: 1.3295x; 1.0287x over previous
//
#include <hip/hip_runtime.h>
#include <hip/hip_bf16.h>
#include <stdint.h>

typedef unsigned short u16;
typedef __attribute__((ext_vector_type(8))) __bf16 bf16x8;
typedef __attribute__((ext_vector_type(4))) float f32x4;
typedef __attribute__((ext_vector_type(16))) float f32x16;

#define AS1(p) ((const __attribute__((address_space(1))) void*)(p))
#define AS3(p) ((__attribute__((address_space(3))) void*)(p))

__device__ __forceinline__ u16 f2bf(float f) {
  union { float f; uint32_t u; } c; c.f = f;
  uint32_t u = c.u;
  u += 0x7fffu + ((u >> 16) & 1u);   // RTNE
  return (u16)(u >> 16);
}

__device__ __forceinline__ float exp2_fast(float x) {
  float r; asm("v_exp_f32 %0, %1" : "=v"(r) : "v"(x)); return r;
}

// ---------------- fused cast fp32 -> bf16: 4 streams, one launch ----------------
__global__ __launch_bounds__(256) void cast4_f32_bf16(
    const float4* __restrict__ s0, ushort4* __restrict__ d0, int n0,
    const float4* __restrict__ s1, ushort4* __restrict__ d1, int n1,
    const float4* __restrict__ s2, ushort4* __restrict__ d2, int n2,
    const float4* __restrict__ s3, ushort4* __restrict__ d3, int n3) {
  int bid = blockIdx.x;
  const float4* src; ushort4* dst; int n4, b0, nb;
  if (bid < 512)       { src = s0; dst = d0; n4 = n0; b0 = 0;    nb = 512; }
  else if (bid < 1024) { src = s1; dst = d1; n4 = n1; b0 = 512;  nb = 512; }
  else if (bid < 1152) { src = s2; dst = d2; n4 = n2; b0 = 1024; nb = 128; }
  else                 { src = s3; dst = d3; n4 = n3; b0 = 1152; nb = 256; }
  int stride = nb * 256;
  for (int i = (bid - b0) * 256 + threadIdx.x; i < n4; i += stride) {
    float4 v = src[i];
    ushort4 o;
    o.x = f2bf(v.x); o.y = f2bf(v.y); o.z = f2bf(v.z); o.w = f2bf(v.w);
    dst[i] = o;
  }
}

// ---------------- fused NT GEMM (q + kv), depth-2 prefetch (3 LDS buffers) ----------------
// 768 blocks (3/CU at 48KB LDS), XCD-swizzled. vmcnt(8): tiles t+1,t+2 stay in flight
// while computing tile t -> ~2 K-steps of latency cover.
__global__ __launch_bounds__(256) void gemm_fused(const u16* __restrict__ xb,
                                                  const u16* __restrict__ wqb,
                                                  u16* __restrict__ qo,
                                                  const u16* __restrict__ cb,
                                                  const u16* __restrict__ wkb,
                                                  u16* __restrict__ kvo,
                                                  float scale_q) {
  __shared__ u16 As[3][128 * 32];
  __shared__ u16 Bs[3][128 * 32];
  const int K = 1024;
  // XCD swizzle: 768 = 8 XCDs x 96 contiguous workloads
  int bid = (blockIdx.x & 7) * 96 + (blockIdx.x >> 3);
  const u16 *A, *B; u16* C; int N, bm, bn; float scale;
  if (bid < 256) { A = xb; B = wqb; C = qo;  N = 1024; bm = bid >> 3; bn = bid & 7;  scale = scale_q; }
  else { int b2 = bid - 256; A = cb; B = wkb; C = kvo; N = 2048; bm = b2 >> 4; bn = b2 & 15; scale = 1.0f; }

  int tid = threadIdx.x;
  int w = tid >> 6, l = tid & 63;
  int wr = w >> 1, wc = w & 1;
  int lr = l & 15, lg = l >> 4;

  const u16* Abase = A + (size_t)(bm * 128 + (l >> 2)) * K + (l & 3) * 8;
  const u16* Bbase = B + (size_t)(bn * 128 + (l >> 2)) * K + (l & 3) * 8;

  f32x4 acc[4][4];
#pragma unroll
  for (int i = 0; i < 4; ++i)
#pragma unroll
    for (int j = 0; j < 4; ++j) acc[i][j] = (f32x4){0.f, 0.f, 0.f, 0.f};

#define STAGE(buf, k0)                                                              \
  {                                                                                 \
    _Pragma("unroll")                                                               \
    for (int t2 = 0; t2 < 2; ++t2) {                                                \
      int seg = w * 2 + t2;                                                         \
      __builtin_amdgcn_global_load_lds(AS1(Abase + (size_t)seg * 16 * K + (k0)),    \
                                       AS3(&As[buf][seg * 512]), 16, 0, 0);         \
      __builtin_amdgcn_global_load_lds(AS1(Bbase + (size_t)seg * 16 * K + (k0)),    \
                                       AS3(&Bs[buf][seg * 512]), 16, 0, 0);         \
    }                                                                               \
  }

  STAGE(0, 0);
  STAGE(1, 32);
  int cur = 0;
  for (int t = 0; t < 32; ++t) {
    if (t < 30) {
      int pf = cur + 2; if (pf >= 3) pf -= 3;   // == (t+2)%3 == (t-1)%3: last read at t-1
      STAGE(pf, (t + 2) * 32);
      asm volatile("s_waitcnt vmcnt(8)" ::: "memory");   // tile t landed; t+1,t+2 in flight
    } else if (t == 30) {
      asm volatile("s_waitcnt vmcnt(4)" ::: "memory");
    } else {
      asm volatile("s_waitcnt vmcnt(0)" ::: "memory");
    }
    __builtin_amdgcn_s_barrier();
    bf16x8 af[4], bb[4];
#pragma unroll
    for (int i = 0; i < 4; ++i)
      af[i] = *(const bf16x8*)(&As[cur][(wr * 64 + i * 16 + lr) * 32 + lg * 8]);
#pragma unroll
    for (int j = 0; j < 4; ++j)
      bb[j] = *(const bf16x8*)(&Bs[cur][(wc * 64 + j * 16 + lr) * 32 + lg * 8]);
    asm volatile("s_waitcnt lgkmcnt(0)" ::: "memory");
    __builtin_amdgcn_sched_barrier(0);
#pragma unroll
    for (int i = 0; i < 4; ++i)
#pragma unroll
      for (int j = 0; j < 4; ++j)
        acc[i][j] = __builtin_amdgcn_mfma_f32_16x16x32_bf16(af[i], bb[j], acc[i][j], 0, 0, 0);
    __builtin_amdgcn_s_barrier();
    if (++cur == 3) cur = 0;
  }
#undef STAGE

#pragma unroll
  for (int i = 0; i < 4; ++i)
#pragma unroll
    for (int j = 0; j < 4; ++j)
#pragma unroll
      for (int r = 0; r < 4; ++r) {
        int row = bm * 128 + wr * 64 + i * 16 + lg * 4 + r;
        int col = bn * 128 + wc * 64 + j * 16 + lr;
        C[(size_t)row * N + col] = f2bf(acc[i][j][r] * scale);
      }
}

// ---------------- flash attention: T15 double-pipeline, 32x32 swapped QK^T ----------------
// grid = 512 blocks (2/CU), 256 thr (4 waves x 32 q-rows). One barrier per tile.
// XCD-swizzled. Cross-half reduces via __shfl_xor (r9's degenerate-input permlane asm
// was the correctness bug candidate — reverted to the proven form).
#define SQ 2048
#define NT 32

__global__ __launch_bounds__(256, 2) void attn_kernel(const u16* __restrict__ Q,
                                                      const u16* __restrict__ KV,
                                                      float* __restrict__ O) {
  __shared__ u16 Ks[2 * 64 * 64];  // [buf][j][d], 16B-block bk holds dblk = bk ^ (j&7)
  __shared__ u16 Vt[2 * 64 * 64];  // [buf][d][j], byte = d*128 + ((j*2) ^ (((d^(d>>3))&7)<<4))

  int wgid = (blockIdx.x & 7) * 64 + (blockIdx.x >> 3);   // bijective 8x64 XCD swizzle
  int qt = wgid & 15;
  int bh = wgid >> 4;
  int b = bh >> 4, h = bh & 15;
  int tid = threadIdx.x;
  int w = tid >> 6, l = tid & 63;
  int li = l & 31, hi = l >> 5;
  int jr = l >> 3, bk = l & 7;

  const u16* kbase = KV + (size_t)b * SQ * 2048 + (size_t)h * 64;
  const u16* vbase = kbase + 1024;
  int i0g = qt * 128 + w * 32;
  const u16* qrow = Q + (size_t)(b * SQ + i0g + li) * 1024 + h * 64;

  bf16x8 qf0 = *(const bf16x8*)(qrow + 0  + hi * 8);
  bf16x8 qf1 = *(const bf16x8*)(qrow + 16 + hi * 8);
  bf16x8 qf2 = *(const bf16x8*)(qrow + 32 + hi * 8);
  bf16x8 qf3 = *(const bf16x8*)(qrow + 48 + hi * 8);

  // prologue: stage tile 0
  {
    const u16* gk0 = kbase + (size_t)(w * 8 + jr) * 2048 + ((bk ^ jr) * 8);
    __builtin_amdgcn_global_load_lds(AS1(gk0), AS3(Ks + w * 512), 16, 0, 0);
    const u16* gk1 = kbase + (size_t)(32 + w * 8 + jr) * 2048 + ((bk ^ jr) * 8);
    __builtin_amdgcn_global_load_lds(AS1(gk1), AS3(Ks + 2048 + w * 512), 16, 0, 0);
  }
  uint4 vregA = *(const uint4*)(vbase + (size_t)(tid >> 3) * 2048 + (tid & 7) * 8);
  uint4 vregB = *(const uint4*)(vbase + (size_t)(32 + (tid >> 3)) * 2048 + (tid & 7) * 8);

  float m_run = -1e30f, l_run = 0.f;
  f32x16 acc0, acc1, zz;
#pragma unroll
  for (int r = 0; r < 16; ++r) { acc0[r] = 0.f; acc1[r] = 0.f; zz[r] = 0.f; }

  auto stage_pf = [&](int t) {
    u16* Vtc = Vt + (t & 1) * 4096;
    int a = tid & 7, jj0 = tid >> 3;
    const u16* pa_ = (const u16*)&vregA;
#pragma unroll
    for (int e = 0; e < 8; ++e)
      *(u16*)((char*)Vtc + (a * 8 + e) * 128 + ((jj0 * 2) ^ ((e ^ a) << 4))) = pa_[e];
    const u16* pb_ = (const u16*)&vregB;
    int jj1 = 32 + jj0;
#pragma unroll
    for (int e = 0; e < 8; ++e)
      *(u16*)((char*)Vtc + (a * 8 + e) * 128 + ((jj1 * 2) ^ ((e ^ a) << 4))) = pb_[e];
    if (t + 1 < NT) {
      int j0n = (t + 1) * 64;
      u16* Ksn = Ks + ((t + 1) & 1) * 4096;
      const u16* gk0 = kbase + (size_t)(j0n + w * 8 + jr) * 2048 + ((bk ^ jr) * 8);
      __builtin_amdgcn_global_load_lds(AS1(gk0), AS3(Ksn + w * 512), 16, 0, 0);
      const u16* gk1 = kbase + (size_t)(j0n + 32 + w * 8 + jr) * 2048 + ((bk ^ jr) * 8);
      __builtin_amdgcn_global_load_lds(AS1(gk1), AS3(Ksn + 2048 + w * 512), 16, 0, 0);
      vregA = *(const uint4*)(vbase + (size_t)(j0n + (tid >> 3)) * 2048 + (tid & 7) * 8);
      vregB = *(const uint4*)(vbase + (size_t)(j0n + 32 + (tid >> 3)) * 2048 + (tid & 7) * 8);
    }
  };

  auto qkt = [&](int t, f32x16& n0, f32x16& n1) {
    const u16* Ksc = Ks + (t & 1) * 4096;
    int swk = (li & 7) << 4;
    __builtin_amdgcn_s_setprio(1);
#pragma unroll
    for (int kb = 0; kb < 4; ++kb) {
      bf16x8 k0 = *(const bf16x8*)((const char*)Ksc + li * 128        + ((kb * 32 + hi * 16) ^ swk));
      bf16x8 k1 = *(const bf16x8*)((const char*)Ksc + (32 + li) * 128 + ((kb * 32 + hi * 16) ^ swk));
      bf16x8 qq = (kb == 0) ? qf0 : (kb == 1) ? qf1 : (kb == 2) ? qf2 : qf3;
      n0 = __builtin_amdgcn_mfma_f32_32x32x16_bf16(k0, qq, (kb == 0) ? zz : n0, 0, 0, 0);
      n1 = __builtin_amdgcn_mfma_f32_32x32x16_bf16(k1, qq, (kb == 0) ? zz : n1, 0, 0, 0);
    }
    __builtin_amdgcn_s_setprio(0);
  };

  auto finish_pv = [&](int tp, const f32x16& sp0, const f32x16& sp1) {
    const u16* Vtp = Vt + (tp & 1) * 4096;
    float p0[16], p1[16];
    float sum = 0.f;
#pragma unroll
    for (int r = 0; r < 16; ++r) { p0[r] = exp2_fast(sp0[r] - m_run); sum += p0[r]; }
#pragma unroll
    for (int r = 0; r < 16; ++r) { p1[r] = exp2_fast(sp1[r] - m_run); sum += p1[r]; }
    sum += __shfl_xor(sum, 32);
    l_run += sum;
    unsigned pw[16];
#pragma unroll
    for (int i2 = 0; i2 < 8; ++i2) {
      asm("v_cvt_pk_bf16_f32 %0, %1, %2" : "=v"(pw[i2])     : "v"(p0[2 * i2]), "v"(p0[2 * i2 + 1]));
      asm("v_cvt_pk_bf16_f32 %0, %1, %2" : "=v"(pw[8 + i2]) : "v"(p1[2 * i2]), "v"(p1[2 * i2 + 1]));
    }
#pragma unroll
    for (int gB = 0; gB < 2; ++gB) {
      int o = gB * 8;
      asm volatile("v_permlane32_swap_b32 %0, %1" : "+v"(pw[o + 0]), "+v"(pw[o + 2]));
      asm volatile("v_permlane32_swap_b32 %0, %1" : "+v"(pw[o + 1]), "+v"(pw[o + 3]));
      asm volatile("v_permlane32_swap_b32 %0, %1" : "+v"(pw[o + 4]), "+v"(pw[o + 6]));
      asm volatile("v_permlane32_swap_b32 %0, %1" : "+v"(pw[o + 5]), "+v"(pw[o + 7]));
    }
    __builtin_amdgcn_s_setprio(1);
#pragma unroll
    for (int kb2 = 0; kb2 < 4; ++kb2) {
      uint4 ufr;
      ufr.x = pw[kb2 * 4 + 0]; ufr.y = pw[kb2 * 4 + 1];
      ufr.z = pw[kb2 * 4 + 2]; ufr.w = pw[kb2 * 4 + 3];
      bf16x8 pa = *(bf16x8*)&ufr;
      int jbyte = kb2 * 32 + hi * 16;
      int d0_ = li, d1_ = 32 + li;
      bf16x8 v0 = *(const bf16x8*)((const char*)Vtp + d0_ * 128 + (jbyte ^ (((d0_ ^ (d0_ >> 3)) & 7) << 4)));
      bf16x8 v1 = *(const bf16x8*)((const char*)Vtp + d1_ * 128 + (jbyte ^ (((d1_ ^ (d1_ >> 3)) & 7) << 4)));
      acc0 = __builtin_amdgcn_mfma_f32_32x32x16_bf16(v0, pa, acc0, 0, 0, 0);
      acc1 = __builtin_amdgcn_mfma_f32_32x32x16_bf16(v1, pa, acc1, 0, 0, 0);
    }
    __builtin_amdgcn_s_setprio(0);
  };

  auto maxred = [&](const f32x16& n0, const f32x16& n1) {
    float pm = fmaxf(n0[14], n0[15]);
#pragma unroll
    for (int r = 0; r < 14; r += 2) pm = fmaxf(fmaxf(pm, n0[r]), n0[r + 1]);   // v_max3
#pragma unroll
    for (int r = 0; r < 16; r += 2) pm = fmaxf(fmaxf(pm, n1[r]), n1[r + 1]);   // v_max3
    pm = fmaxf(pm, __shfl_xor(pm, 32));
    if (!__all(pm <= m_run + 8.0f)) {
      float mnew = fmaxf(m_run, pm);
      float esc = exp2_fast(m_run - mnew);
      m_run = mnew;
      l_run *= esc;
#pragma unroll
      for (int r = 0; r < 16; ++r) { acc0[r] *= esc; acc1[r] *= esc; }
    }
  };

  f32x16 sa0, sa1, sb0, sb1;
  __syncthreads();                 // K(0) landed
  stage_pf(0);
  qkt(0, sa0, sa1);
  maxred(sa0, sa1);
  for (int t = 1; t < NT - 1; t += 2) {
    __syncthreads();
    stage_pf(t);
    qkt(t, sb0, sb1);
    finish_pv(t - 1, sa0, sa1);
    maxred(sb0, sb1);
    __syncthreads();
    stage_pf(t + 1);
    qkt(t + 1, sa0, sa1);
    finish_pv(t, sb0, sb1);
    maxred(sa0, sa1);
  }
  __syncthreads();
  stage_pf(NT - 1);
  qkt(NT - 1, sb0, sb1);
  finish_pv(NT - 2, sa0, sa1);
  maxred(sb0, sb1);
  __syncthreads();
  finish_pv(NT - 1, sb0, sb1);

  float inv = 1.f / l_run;
  float* orow = O + ((size_t)(b * SQ + i0g + li) * 1024 + h * 64);
#pragma unroll
  for (int g = 0; g < 4; ++g) {
    f32x4 o0, o1;
#pragma unroll
    for (int q_ = 0; q_ < 4; ++q_) {
      o0[q_] = acc0[g * 4 + q_] * inv;
      o1[q_] = acc1[g * 4 + q_] * inv;
    }
    *(f32x4*)(orow + 8 * g + 4 * hi) = o0;
    *(f32x4*)(orow + 32 + 8 * g + 4 * hi) = o1;
  }
}

extern "C" void kernel_launch(void* const* d_in, const int* in_sizes, int n_in,
                              void* d_out, int out_size, void* d_ws, size_t ws_size,
                              hipStream_t stream) {
  (void)in_sizes; (void)n_in; (void)out_size; (void)ws_size;
  const float* x   = (const float*)d_in[0];
  const float* ctx = (const float*)d_in[1];
  const float* Wq  = (const float*)d_in[2];
  const float* Wkv = (const float*)d_in[3];
  float* out = (float*)d_out;
  char* ws = (char*)d_ws;

  u16* xb  = (u16*)(ws);                       // x bf16   [4096][1024]  8 MB
  u16* cb  = (u16*)(ws + (8ull  << 20));       // ctx bf16 [4096][1024]  8 MB
  u16* wqb = (u16*)(ws + (16ull << 20));       // Wq bf16  [1024][1024]  2 MB
  u16* wkb = (u16*)(ws + (18ull << 20));       // Wkv bf16 [2048][1024]  4 MB
  u16* q   = (u16*)(ws + (22ull << 20));       // q bf16, pre-scaled by 0.125*log2(e)
  u16* kv  = (u16*)(ws + (30ull << 20));       // kv bf16  [4096][2048] 16 MB

  cast4_f32_bf16<<<1408, 256, 0, stream>>>(
      (const float4*)x,   (ushort4*)xb,  (4096 * 1024) / 4,
      (const float4*)ctx, (ushort4*)cb,  (4096 * 1024) / 4,
      (const float4*)Wq,  (ushort4*)wqb, (1024 * 1024) / 4,
      (const float4*)Wkv, (ushort4*)wkb, (2048 * 1024) / 4);

  gemm_fused<<<768, 256, 0, stream>>>(xb, wqb, q, cb, wkb, kv, 0.125f * 1.44269504f);

  attn_kernel<<<512, 256, 0, stream>>>(q, kv, out);
}

// Round 11
// 99.007 us; speedup vs baseline: 1.3949x; 1.0492x over previous
//
#include <hip/hip_runtime.h>
#include <hip/hip_bf16.h>
#include <stdint.h>

typedef unsigned short u16;
typedef __attribute__((ext_vector_type(8))) __bf16 bf16x8;
typedef __attribute__((ext_vector_type(4))) float f32x4;
typedef __attribute__((ext_vector_type(16))) float f32x16;

#define AS1(p) ((const __attribute__((address_space(1))) void*)(p))
#define AS3(p) ((__attribute__((address_space(3))) void*)(p))

__device__ __forceinline__ u16 f2bf(float f) {
  union { float f; uint32_t u; } c; c.f = f;
  uint32_t u = c.u;
  u += 0x7fffu + ((u >> 16) & 1u);   // RTNE
  return (u16)(u >> 16);
}

__device__ __forceinline__ float exp2_fast(float x) {
  float r; asm("v_exp_f32 %0, %1" : "=v"(r) : "v"(x)); return r;
}

// ---------------- fused cast fp32 -> bf16: 4 streams, one launch ----------------
__global__ __launch_bounds__(256) void cast4_f32_bf16(
    const float4* __restrict__ s0, ushort4* __restrict__ d0, int n0,
    const float4* __restrict__ s1, ushort4* __restrict__ d1, int n1,
    const float4* __restrict__ s2, ushort4* __restrict__ d2, int n2,
    const float4* __restrict__ s3, ushort4* __restrict__ d3, int n3) {
  int bid = blockIdx.x;
  const float4* src; ushort4* dst; int n4, b0, nb;
  if (bid < 512)       { src = s0; dst = d0; n4 = n0; b0 = 0;    nb = 512; }
  else if (bid < 1024) { src = s1; dst = d1; n4 = n1; b0 = 512;  nb = 512; }
  else if (bid < 1152) { src = s2; dst = d2; n4 = n2; b0 = 1024; nb = 128; }
  else                 { src = s3; dst = d3; n4 = n3; b0 = 1152; nb = 256; }
  int stride = nb * 256;
  for (int i = (bid - b0) * 256 + threadIdx.x; i < n4; i += stride) {
    float4 v = src[i];
    ushort4 o;
    o.x = f2bf(v.x); o.y = f2bf(v.y); o.z = f2bf(v.z); o.w = f2bf(v.w);
    dst[i] = o;
  }
}

// ---------------- fused NT GEMM (q + kv), depth-2 prefetch (3 LDS buffers) ----------------
__global__ __launch_bounds__(256) void gemm_fused(const u16* __restrict__ xb,
                                                  const u16* __restrict__ wqb,
                                                  u16* __restrict__ qo,
                                                  const u16* __restrict__ cb,
                                                  const u16* __restrict__ wkb,
                                                  u16* __restrict__ kvo,
                                                  float scale_q) {
  __shared__ u16 As[3][128 * 32];
  __shared__ u16 Bs[3][128 * 32];
  const int K = 1024;
  int bid = (blockIdx.x & 7) * 96 + (blockIdx.x >> 3);
  const u16 *A, *B; u16* C; int N, bm, bn; float scale;
  if (bid < 256) { A = xb; B = wqb; C = qo;  N = 1024; bm = bid >> 3; bn = bid & 7;  scale = scale_q; }
  else { int b2 = bid - 256; A = cb; B = wkb; C = kvo; N = 2048; bm = b2 >> 4; bn = b2 & 15; scale = 1.0f; }

  int tid = threadIdx.x;
  int w = tid >> 6, l = tid & 63;
  int wr = w >> 1, wc = w & 1;
  int lr = l & 15, lg = l >> 4;

  const u16* Abase = A + (size_t)(bm * 128 + (l >> 2)) * K + (l & 3) * 8;
  const u16* Bbase = B + (size_t)(bn * 128 + (l >> 2)) * K + (l & 3) * 8;

  f32x4 acc[4][4];
#pragma unroll
  for (int i = 0; i < 4; ++i)
#pragma unroll
    for (int j = 0; j < 4; ++j) acc[i][j] = (f32x4){0.f, 0.f, 0.f, 0.f};

#define STAGE(buf, k0)                                                              \
  {                                                                                 \
    _Pragma("unroll")                                                               \
    for (int t2 = 0; t2 < 2; ++t2) {                                                \
      int seg = w * 2 + t2;                                                         \
      __builtin_amdgcn_global_load_lds(AS1(Abase + (size_t)seg * 16 * K + (k0)),    \
                                       AS3(&As[buf][seg * 512]), 16, 0, 0);         \
      __builtin_amdgcn_global_load_lds(AS1(Bbase + (size_t)seg * 16 * K + (k0)),    \
                                       AS3(&Bs[buf][seg * 512]), 16, 0, 0);         \
    }                                                                               \
  }

  STAGE(0, 0);
  STAGE(1, 32);
  int cur = 0;
  for (int t = 0; t < 32; ++t) {
    if (t < 30) {
      int pf = cur + 2; if (pf >= 3) pf -= 3;
      STAGE(pf, (t + 2) * 32);
      asm volatile("s_waitcnt vmcnt(8)" ::: "memory");
    } else if (t == 30) {
      asm volatile("s_waitcnt vmcnt(4)" ::: "memory");
    } else {
      asm volatile("s_waitcnt vmcnt(0)" ::: "memory");
    }
    __builtin_amdgcn_s_barrier();
    bf16x8 af[4], bb[4];
#pragma unroll
    for (int i = 0; i < 4; ++i)
      af[i] = *(const bf16x8*)(&As[cur][(wr * 64 + i * 16 + lr) * 32 + lg * 8]);
#pragma unroll
    for (int j = 0; j < 4; ++j)
      bb[j] = *(const bf16x8*)(&Bs[cur][(wc * 64 + j * 16 + lr) * 32 + lg * 8]);
    asm volatile("s_waitcnt lgkmcnt(0)" ::: "memory");
    __builtin_amdgcn_sched_barrier(0);
#pragma unroll
    for (int i = 0; i < 4; ++i)
#pragma unroll
      for (int j = 0; j < 4; ++j)
        acc[i][j] = __builtin_amdgcn_mfma_f32_16x16x32_bf16(af[i], bb[j], acc[i][j], 0, 0, 0);
    __builtin_amdgcn_s_barrier();
    if (++cur == 3) cur = 0;
  }
#undef STAGE

#pragma unroll
  for (int i = 0; i < 4; ++i)
#pragma unroll
    for (int j = 0; j < 4; ++j)
#pragma unroll
      for (int r = 0; r < 4; ++r) {
        int row = bm * 128 + wr * 64 + i * 16 + lg * 4 + r;
        int col = bn * 128 + wc * 64 + j * 16 + lr;
        C[(size_t)row * N + col] = f2bf(acc[i][j][r] * scale);
      }
}

// ---------------- flash attention: KVBLK=128, 32x32 swapped QK^T ----------------
// grid = 512 blocks (2/CU), 256 thr (4 waves x 32 q-rows). Per 128 kv: ONE barrier pair,
// ONE max-reduce/rescale (was 2 at KVBLK=64) and long MFMA/exp phases for ILP.
// XCD-swizzled. Q pre-scaled by HD^-0.5*log2(e); exp2-domain softmax, defer-max THR=8.
#define SQ 2048
#define NTT 16

__global__ __launch_bounds__(256, 2) void attn_kernel(const u16* __restrict__ Q,
                                                      const u16* __restrict__ KV,
                                                      float* __restrict__ O) {
  __shared__ u16 Ks[2][128 * 64];  // [buf][j][d], 16B-block bk holds dblk = bk ^ (j&7)
  __shared__ u16 Vt[2][64 * 128];  // [buf][d][j], byte = d*256 + ((j*2) ^ (((d^(d>>3))&7)<<4))

  int wgid = (blockIdx.x & 7) * 64 + (blockIdx.x >> 3);   // bijective 8x64 XCD swizzle
  int qt = wgid & 15;
  int bh = wgid >> 4;
  int b = bh >> 4, h = bh & 15;
  int tid = threadIdx.x;
  int w = tid >> 6, l = tid & 63;
  int li = l & 31, hi = l >> 5;
  int jr = l >> 3, bk = l & 7;
  int a7 = tid & 7, jj = tid >> 3;   // V staging coords

  const u16* kbase = KV + (size_t)b * SQ * 2048 + (size_t)h * 64;
  const u16* vbase = kbase + 1024;
  int i0g = qt * 128 + w * 32;
  const u16* qrow = Q + (size_t)(b * SQ + i0g + li) * 1024 + h * 64;

  bf16x8 qf0 = *(const bf16x8*)(qrow + 0  + hi * 8);
  bf16x8 qf1 = *(const bf16x8*)(qrow + 16 + hi * 8);
  bf16x8 qf2 = *(const bf16x8*)(qrow + 32 + hi * 8);
  bf16x8 qf3 = *(const bf16x8*)(qrow + 48 + hi * 8);

  // prologue: stage K tile 0 (128 rows, 4 gload_lds/thread); V tile 0 -> regs
#pragma unroll
  for (int c = 0; c < 4; ++c) {
    const u16* gk = kbase + (size_t)(c * 32 + w * 8 + jr) * 2048 + ((bk ^ jr) * 8);
    __builtin_amdgcn_global_load_lds(AS1(gk), AS3(&Ks[0][c * 2048 + w * 512]), 16, 0, 0);
  }
  uint4 vrA = *(const uint4*)(vbase + (size_t)(jj +  0) * 2048 + a7 * 8);
  uint4 vrB = *(const uint4*)(vbase + (size_t)(jj + 32) * 2048 + a7 * 8);
  uint4 vrC = *(const uint4*)(vbase + (size_t)(jj + 64) * 2048 + a7 * 8);
  uint4 vrD = *(const uint4*)(vbase + (size_t)(jj + 96) * 2048 + a7 * 8);

  float m_run = -1e30f, l_run = 0.f;
  f32x16 acc0, acc1, zz;
#pragma unroll
  for (int r = 0; r < 16; ++r) { acc0[r] = 0.f; acc1[r] = 0.f; zz[r] = 0.f; }

  int swk = (li & 7) << 4;
  int sw0 = ((li ^ (li >> 3)) & 7) << 4;          // Vt read swizzle, d = li
  int sw1 = (((32 + li) ^ ((32 + li) >> 3)) & 7) << 4;  // d = 32+li

  for (int t = 0; t < NTT; ++t) {
    u16* Ksc = (u16*)Ks[t & 1];
    char* Vtc = (char*)Vt[t & 1];
    __syncthreads();               // K(t),V(t) landed (vmcnt drain); both bufs' old reads done
    // ---- V transpose-store: 32 scalar b16 (2-way bank max: slot (e^a7) varies per e)
    {
      const u16* pA = (const u16*)&vrA;
      const u16* pB = (const u16*)&vrB;
      const u16* pC = (const u16*)&vrC;
      const u16* pD = (const u16*)&vrD;
#pragma unroll
      for (int e = 0; e < 8; ++e) {
        int dbyte = (a7 * 8 + e) * 256, sw = (e ^ a7) << 4;
        *(u16*)(Vtc + dbyte + (((jj * 2) +   0) ^ sw)) = pA[e];
        *(u16*)(Vtc + dbyte + (((jj * 2) +  64) ^ sw)) = pB[e];
        *(u16*)(Vtc + dbyte + (((jj * 2) + 128) ^ sw)) = pC[e];
        *(u16*)(Vtc + dbyte + (((jj * 2) + 192) ^ sw)) = pD[e];
      }
    }
    asm volatile("s_waitcnt lgkmcnt(0)" ::: "memory");   // my ds_writes committed
    __builtin_amdgcn_s_barrier();                        // Vt[cur] visible (no vmcnt drain)
    // ---- prefetch tile t+1 (rides through compute; drained by next top-sync)
    if (t + 1 < NTT) {
      int j0n = (t + 1) * 128;
      u16* Ksn = (u16*)Ks[(t + 1) & 1];
#pragma unroll
      for (int c = 0; c < 4; ++c) {
        const u16* gk = kbase + (size_t)(j0n + c * 32 + w * 8 + jr) * 2048 + ((bk ^ jr) * 8);
        __builtin_amdgcn_global_load_lds(AS1(gk), AS3(&Ksn[c * 2048 + w * 512]), 16, 0, 0);
      }
      vrA = *(const uint4*)(vbase + (size_t)(j0n + jj +  0) * 2048 + a7 * 8);
      vrB = *(const uint4*)(vbase + (size_t)(j0n + jj + 32) * 2048 + a7 * 8);
      vrC = *(const uint4*)(vbase + (size_t)(j0n + jj + 64) * 2048 + a7 * 8);
      vrD = *(const uint4*)(vbase + (size_t)(j0n + jj + 96) * 2048 + a7 * 8);
    }
    // ---- swapped QK^T: 16 MFMAs, 4 independent chains (s_jb covers j = jb*32 + crow)
    f32x16 s0, s1, s2, s3;
    __builtin_amdgcn_s_setprio(1);
#define QKT1(sv, JB)                                                             \
    {                                                                            \
      const char* kr = (const char*)Ksc + ((JB) * 32 + li) * 128;                \
      bf16x8 kk;                                                                 \
      kk = *(const bf16x8*)(kr + ((0  + hi * 16) ^ swk));                        \
      sv = __builtin_amdgcn_mfma_f32_32x32x16_bf16(kk, qf0, zz, 0, 0, 0);        \
      kk = *(const bf16x8*)(kr + ((32 + hi * 16) ^ swk));                        \
      sv = __builtin_amdgcn_mfma_f32_32x32x16_bf16(kk, qf1, sv, 0, 0, 0);        \
      kk = *(const bf16x8*)(kr + ((64 + hi * 16) ^ swk));                        \
      sv = __builtin_amdgcn_mfma_f32_32x32x16_bf16(kk, qf2, sv, 0, 0, 0);        \
      kk = *(const bf16x8*)(kr + ((96 + hi * 16) ^ swk));                        \
      sv = __builtin_amdgcn_mfma_f32_32x32x16_bf16(kk, qf3, sv, 0, 0, 0);        \
    }
    QKT1(s0, 0)
    QKT1(s1, 1)
    QKT1(s2, 2)
    QKT1(s3, 3)
#undef QKT1
    __builtin_amdgcn_s_setprio(0);
    // ---- ONE max-reduce over 64 values (v_max3-friendly pairs)
    float pm = fmaxf(s0[14], s0[15]);
#pragma unroll
    for (int r = 0; r < 14; r += 2) pm = fmaxf(fmaxf(pm, s0[r]), s0[r + 1]);
#pragma unroll
    for (int r = 0; r < 16; r += 2) pm = fmaxf(fmaxf(pm, s1[r]), s1[r + 1]);
#pragma unroll
    for (int r = 0; r < 16; r += 2) pm = fmaxf(fmaxf(pm, s2[r]), s2[r + 1]);
#pragma unroll
    for (int r = 0; r < 16; r += 2) pm = fmaxf(fmaxf(pm, s3[r]), s3[r + 1]);
    pm = fmaxf(pm, __shfl_xor(pm, 32));
    if (!__all(pm <= m_run + 8.0f)) {
      float mnew = fmaxf(m_run, pm);
      float esc = exp2_fast(m_run - mnew);
      m_run = mnew;
      l_run *= esc;
#pragma unroll
      for (int r = 0; r < 16; ++r) { acc0[r] *= esc; acc1[r] *= esc; }
    }
    // ---- exp in place (64 independent) + sum
    float sum = 0.f;
#pragma unroll
    for (int r = 0; r < 16; ++r) { s0[r] = exp2_fast(s0[r] - m_run); sum += s0[r]; }
#pragma unroll
    for (int r = 0; r < 16; ++r) { s1[r] = exp2_fast(s1[r] - m_run); sum += s1[r]; }
#pragma unroll
    for (int r = 0; r < 16; ++r) { s2[r] = exp2_fast(s2[r] - m_run); sum += s2[r]; }
#pragma unroll
    for (int r = 0; r < 16; ++r) { s3[r] = exp2_fast(s3[r] - m_run); sum += s3[r]; }
    sum += __shfl_xor(sum, 32);
    l_run += sum;
    // ---- pack P -> bf16 A-frag layout (cvt_pk + permlane32_swap), 4 groups of 8 words
    unsigned pw[32];
#pragma unroll
    for (int i2 = 0; i2 < 8; ++i2) {
      asm("v_cvt_pk_bf16_f32 %0, %1, %2" : "=v"(pw[i2])      : "v"(s0[2 * i2]), "v"(s0[2 * i2 + 1]));
      asm("v_cvt_pk_bf16_f32 %0, %1, %2" : "=v"(pw[8 + i2])  : "v"(s1[2 * i2]), "v"(s1[2 * i2 + 1]));
      asm("v_cvt_pk_bf16_f32 %0, %1, %2" : "=v"(pw[16 + i2]) : "v"(s2[2 * i2]), "v"(s2[2 * i2 + 1]));
      asm("v_cvt_pk_bf16_f32 %0, %1, %2" : "=v"(pw[24 + i2]) : "v"(s3[2 * i2]), "v"(s3[2 * i2 + 1]));
    }
#pragma unroll
    for (int gB = 0; gB < 4; ++gB) {
      int o = gB * 8;
      asm volatile("v_permlane32_swap_b32 %0, %1" : "+v"(pw[o + 0]), "+v"(pw[o + 2]));
      asm volatile("v_permlane32_swap_b32 %0, %1" : "+v"(pw[o + 1]), "+v"(pw[o + 3]));
      asm volatile("v_permlane32_swap_b32 %0, %1" : "+v"(pw[o + 4]), "+v"(pw[o + 6]));
      asm volatile("v_permlane32_swap_b32 %0, %1" : "+v"(pw[o + 5]), "+v"(pw[o + 7]));
    }
    // ---- PV as O^T: 16 MFMAs over j=0..127
    __builtin_amdgcn_s_setprio(1);
#pragma unroll
    for (int jsp = 0; jsp < 8; ++jsp) {
      uint4 ufr;
      ufr.x = pw[jsp * 4 + 0]; ufr.y = pw[jsp * 4 + 1];
      ufr.z = pw[jsp * 4 + 2]; ufr.w = pw[jsp * 4 + 3];
      bf16x8 pa = *(bf16x8*)&ufr;
      int jbyte = jsp * 32 + hi * 16;
      bf16x8 v0 = *(const bf16x8*)(Vtc + li * 256 + (jbyte ^ sw0));
      bf16x8 v1 = *(const bf16x8*)(Vtc + (32 + li) * 256 + (jbyte ^ sw1));
      acc0 = __builtin_amdgcn_mfma_f32_32x32x16_bf16(v0, pa, acc0, 0, 0, 0);
      acc1 = __builtin_amdgcn_mfma_f32_32x32x16_bf16(v1, pa, acc1, 0, 0, 0);
    }
    __builtin_amdgcn_s_setprio(0);
  }
  // ---- epilogue: O^T layout, d = 8g + 4hi + r (+32 for acc1), col(q-row) = li
  float inv = 1.f / l_run;
  float* orow = O + ((size_t)(b * SQ + i0g + li) * 1024 + h * 64);
#pragma unroll
  for (int g = 0; g < 4; ++g) {
    f32x4 o0, o1;
#pragma unroll
    for (int q_ = 0; q_ < 4; ++q_) {
      o0[q_] = acc0[g * 4 + q_] * inv;
      o1[q_] = acc1[g * 4 + q_] * inv;
    }
    *(f32x4*)(orow + 8 * g + 4 * hi) = o0;
    *(f32x4*)(orow + 32 + 8 * g + 4 * hi) = o1;
  }
}

extern "C" void kernel_launch(void* const* d_in, const int* in_sizes, int n_in,
                              void* d_out, int out_size, void* d_ws, size_t ws_size,
                              hipStream_t stream) {
  (void)in_sizes; (void)n_in; (void)out_size; (void)ws_size;
  const float* x   = (const float*)d_in[0];
  const float* ctx = (const float*)d_in[1];
  const float* Wq  = (const float*)d_in[2];
  const float* Wkv = (const float*)d_in[3];
  float* out = (float*)d_out;
  char* ws = (char*)d_ws;

  u16* xb  = (u16*)(ws);                       // x bf16   [4096][1024]  8 MB
  u16* cb  = (u16*)(ws + (8ull  << 20));       // ctx bf16 [4096][1024]  8 MB
  u16* wqb = (u16*)(ws + (16ull << 20));       // Wq bf16  [1024][1024]  2 MB
  u16* wkb = (u16*)(ws + (18ull << 20));       // Wkv bf16 [2048][1024]  4 MB
  u16* q   = (u16*)(ws + (22ull << 20));       // q bf16, pre-scaled by 0.125*log2(e)
  u16* kv  = (u16*)(ws + (30ull << 20));       // kv bf16  [4096][2048] 16 MB

  cast4_f32_bf16<<<1408, 256, 0, stream>>>(
      (const float4*)x,   (ushort4*)xb,  (4096 * 1024) / 4,
      (const float4*)ctx, (ushort4*)cb,  (4096 * 1024) / 4,
      (const float4*)Wq,  (ushort4*)wqb, (1024 * 1024) / 4,
      (const float4*)Wkv, (ushort4*)wkb, (2048 * 1024) / 4);

  gemm_fused<<<768, 256, 0, stream>>>(xb, wqb, q, cb, wkb, kv, 0.125f * 1.44269504f);

  attn_kernel<<<512, 256, 0, stream>>>(q, kv, out);
}